// Round 1
// baseline (467.340 us; speedup 1.0000x reference)
//
#include <hip/hip_runtime.h>
#include <hip/hip_bf16.h>
#include <math.h>

#define HIDDEN 2048
#define EINTER 1024
#define NEXP 8
#define VOCAB 100000
#define TPE (VOCAB / NEXP)   // 12500

typedef unsigned short u16;
typedef __attribute__((ext_vector_type(8))) short short8;   // 8 bf16 bit patterns (4 VGPRs)
typedef __attribute__((ext_vector_type(4))) float f32x4;

__device__ __forceinline__ u16 f2bf(float f) {
  union { float f; unsigned u; } v; v.f = f;
  unsigned r = v.u + 0x7fffu + ((v.u >> 16) & 1u);   // RNE, finite inputs only
  return (u16)(r >> 16);
}

// ws header (ints): [0..7]=cnt[e], [8..15]=off[e], [16]=n_tiles, [32..95]=worklist
// byte 1024: src_of[T]  (int)
// then (256-aligned): Xg bf16 [T][HIDDEN], then H bf16 [T][EINTER]

__global__ void route_kernel(const int* __restrict__ ids, int T,
                             int* __restrict__ hdr, int* __restrict__ src_of) {
  __shared__ int cnt[NEXP], cur[NEXP];
  int tid = threadIdx.x;
  if (tid < NEXP) cnt[tid] = 0;
  __syncthreads();
  for (int t = tid; t < T; t += blockDim.x) {
    int id = ids[t]; id = min(max(id, 0), VOCAB - 1);
    int e = min(id / TPE, NEXP - 1);
    atomicAdd(&cnt[e], 1);
  }
  __syncthreads();
  if (tid == 0) {
    int acc = 0, nt = 0;
    for (int e = 0; e < NEXP; e++) {
      cur[e] = acc;
      hdr[e] = cnt[e];
      hdr[8 + e] = acc;
      int tiles = (cnt[e] + 127) >> 7;
      for (int m = 0; m < tiles; m++) hdr[32 + nt++] = (m << 3) | e;
      acc += cnt[e];
    }
    hdr[16] = nt;
  }
  __syncthreads();
  for (int t = tid; t < T; t += blockDim.x) {
    int id = ids[t]; id = min(max(id, 0), VOCAB - 1);
    int e = min(id / TPE, NEXP - 1);
    int pos = atomicAdd(&cur[e], 1);
    src_of[pos] = t;
  }
}

// one block per gathered row: fp32 -> bf16, 8 elems/thread
__global__ void gather_kernel(const float* __restrict__ x,
                              const int* __restrict__ src_of,
                              u16* __restrict__ Xg) {
  int p = blockIdx.x;
  int t = src_of[p];
  int c = threadIdx.x;                       // 0..255
  const float4* src = (const float4*)(x + (size_t)t * HIDDEN) + c * 2;
  float4 a = src[0], b = src[1];
  union { u16 s[8]; uint4 v; } o;
  o.s[0] = f2bf(a.x); o.s[1] = f2bf(a.y); o.s[2] = f2bf(a.z); o.s[3] = f2bf(a.w);
  o.s[4] = f2bf(b.x); o.s[5] = f2bf(b.y); o.s[6] = f2bf(b.z); o.s[7] = f2bf(b.w);
  *((uint4*)(Xg + (size_t)p * HIDDEN) + c) = o.v;
}

// fused gate/up GEMM + silu: H[p][n] = silu(Xg@Wg) * (Xg@Wu), bf16 out
__launch_bounds__(256, 2)
__global__ void gemm1_kernel(const u16* __restrict__ Xg,
                             const float* __restrict__ gate,
                             const float* __restrict__ up,
                             u16* __restrict__ H,
                             const int* __restrict__ hdr, int T) {
  int ntile = hdr[16];
  int w = blockIdx.x;
  if (w >= ntile) return;
  int packed = hdr[32 + w];
  int e = packed & 7, mt = packed >> 3;
  int Me = hdr[e], base = hdr[8 + e];
  int row0 = base + (mt << 7);
  int valid = min(128, base + Me - row0);
  int n0 = blockIdx.y << 7;                  // 0..896

  __shared__ u16  As[128][40];               // bf16, pad 40 (2-way max -> free)
  __shared__ float Bg[32][129];              // fp32 [k][n], stride 129 -> 2-way reads
  __shared__ float Bu[32][129];

  int tid = threadIdx.x;
  int lane = tid & 63, wv = tid >> 6;
  int wm = wv >> 1, wn = wv & 1;
  int quad = lane >> 4, ln = lane & 15;

  f32x4 accG[4][4] = {};
  f32x4 accU[4][4] = {};

  const float* gbase = gate + (size_t)e * (HIDDEN * (size_t)EINTER) + n0;
  const float* ubase = up   + (size_t)e * (HIDDEN * (size_t)EINTER) + n0;

  for (int k0 = 0; k0 < HIDDEN; k0 += 32) {
    __syncthreads();
    // ---- stage A (bf16 gathered rows; mask rows past end of buffer) ----
    #pragma unroll
    for (int it = 0; it < 2; it++) {
      int s = tid + (it << 8);
      int row = s >> 2, ch = s & 3;
      int gr = row0 + row;
      uint4 v = {0u, 0u, 0u, 0u};
      if (gr < T) v = *(const uint4*)(Xg + (size_t)gr * HIDDEN + k0 + (ch << 3));
      *(uint4*)&As[row][ch << 3] = v;
    }
    // ---- stage Bg/Bu (fp32, coalesced float4 reads, scalar LDS writes) ----
    {
      int n4 = (tid & 31) << 2;
      int kb = tid >> 5;
      #pragma unroll
      for (int it = 0; it < 4; it++) {
        int k = kb + (it << 3);
        const float4 g4 = *(const float4*)(gbase + (size_t)(k0 + k) * EINTER + n4);
        const float4 u4 = *(const float4*)(ubase + (size_t)(k0 + k) * EINTER + n4);
        Bg[k][n4] = g4.x; Bg[k][n4 + 1] = g4.y; Bg[k][n4 + 2] = g4.z; Bg[k][n4 + 3] = g4.w;
        Bu[k][n4] = u4.x; Bu[k][n4 + 1] = u4.y; Bu[k][n4 + 2] = u4.z; Bu[k][n4 + 3] = u4.w;
      }
    }
    __syncthreads();
    // ---- fragments + MFMA ----
    short8 a[4], bg[4], bu[4];
    #pragma unroll
    for (int im = 0; im < 4; im++) {
      int m = (wm << 6) + (im << 4) + ln;
      a[im] = *(const short8*)&As[m][quad << 3];
    }
    #pragma unroll
    for (int in = 0; in < 4; in++) {
      int n = (wn << 6) + (in << 4) + ln;
      short8 tg, tu;
      #pragma unroll
      for (int j = 0; j < 8; j++) {
        tg[j] = (short)f2bf(Bg[(quad << 3) + j][n]);
        tu[j] = (short)f2bf(Bu[(quad << 3) + j][n]);
      }
      bg[in] = tg; bu[in] = tu;
    }
    #pragma unroll
    for (int im = 0; im < 4; im++) {
      #pragma unroll
      for (int in = 0; in < 4; in++) {
        accG[im][in] = __builtin_amdgcn_mfma_f32_16x16x32_bf16(a[im], bg[in], accG[im][in], 0, 0, 0);
        accU[im][in] = __builtin_amdgcn_mfma_f32_16x16x32_bf16(a[im], bu[in], accU[im][in], 0, 0, 0);
      }
    }
  }
  // ---- epilogue: h = silu(g)*u, store bf16 (mask partial tile) ----
  #pragma unroll
  for (int im = 0; im < 4; im++) {
    #pragma unroll
    for (int in = 0; in < 4; in++) {
      #pragma unroll
      for (int r = 0; r < 4; r++) {
        int rl = (wm << 6) + (im << 4) + (quad << 2) + r;
        if (rl < valid) {
          int col = n0 + (wn << 6) + (in << 4) + ln;
          float g = accG[im][in][r], u = accU[im][in][r];
          float s = 1.0f / (1.0f + __expf(-g));
          H[(size_t)(row0 + rl) * EINTER + col] = f2bf(g * s * u);
        }
      }
    }
  }
}

// down GEMM: out[src_of[p]][n] = H[p] @ Wd[e]
__launch_bounds__(256, 2)
__global__ void gemm2_kernel(const u16* __restrict__ Hb,
                             const float* __restrict__ down,
                             float* __restrict__ out,
                             const int* __restrict__ src_of,
                             const int* __restrict__ hdr, int T) {
  int ntile = hdr[16];
  int w = blockIdx.x;
  if (w >= ntile) return;
  int packed = hdr[32 + w];
  int e = packed & 7, mt = packed >> 3;
  int Me = hdr[e], base = hdr[8 + e];
  int row0 = base + (mt << 7);
  int valid = min(128, base + Me - row0);
  int n0 = blockIdx.y << 7;                  // 0..1920

  __shared__ u16  As[128][40];
  __shared__ float Bd[32][129];

  int tid = threadIdx.x;
  int lane = tid & 63, wv = tid >> 6;
  int wm = wv >> 1, wn = wv & 1;
  int quad = lane >> 4, ln = lane & 15;

  f32x4 accD[4][4] = {};

  const float* dbase = down + (size_t)e * (EINTER * (size_t)HIDDEN) + n0;

  for (int k0 = 0; k0 < EINTER; k0 += 32) {
    __syncthreads();
    #pragma unroll
    for (int it = 0; it < 2; it++) {
      int s = tid + (it << 8);
      int row = s >> 2, ch = s & 3;
      int gr = row0 + row;
      uint4 v = {0u, 0u, 0u, 0u};
      if (gr < T) v = *(const uint4*)(Hb + (size_t)gr * EINTER + k0 + (ch << 3));
      *(uint4*)&As[row][ch << 3] = v;
    }
    {
      int n4 = (tid & 31) << 2;
      int kb = tid >> 5;
      #pragma unroll
      for (int it = 0; it < 4; it++) {
        int k = kb + (it << 3);
        const float4 d4 = *(const float4*)(dbase + (size_t)(k0 + k) * HIDDEN + n4);
        Bd[k][n4] = d4.x; Bd[k][n4 + 1] = d4.y; Bd[k][n4 + 2] = d4.z; Bd[k][n4 + 3] = d4.w;
      }
    }
    __syncthreads();
    short8 a[4], bd[4];
    #pragma unroll
    for (int im = 0; im < 4; im++) {
      int m = (wm << 6) + (im << 4) + ln;
      a[im] = *(const short8*)&As[m][quad << 3];
    }
    #pragma unroll
    for (int in = 0; in < 4; in++) {
      int n = (wn << 6) + (in << 4) + ln;
      short8 td;
      #pragma unroll
      for (int j = 0; j < 8; j++) td[j] = (short)f2bf(Bd[(quad << 3) + j][n]);
      bd[in] = td;
    }
    #pragma unroll
    for (int im = 0; im < 4; im++) {
      #pragma unroll
      for (int in = 0; in < 4; in++) {
        accD[im][in] = __builtin_amdgcn_mfma_f32_16x16x32_bf16(a[im], bd[in], accD[im][in], 0, 0, 0);
      }
    }
  }
  // scatter rows back to token order
  #pragma unroll
  for (int im = 0; im < 4; im++) {
    #pragma unroll
    for (int r = 0; r < 4; r++) {
      int rl = (wm << 6) + (im << 4) + (quad << 2) + r;
      if (rl < valid) {
        int t = src_of[row0 + rl];
        #pragma unroll
        for (int in = 0; in < 4; in++) {
          int col = n0 + (wn << 6) + (in << 4) + ln;
          out[(size_t)t * HIDDEN + col] = accD[im][in][r];
        }
      }
    }
  }
}

extern "C" void kernel_launch(void* const* d_in, const int* in_sizes, int n_in,
                              void* d_out, int out_size, void* d_ws, size_t ws_size,
                              hipStream_t stream) {
  const float* x    = (const float*)d_in[0];
  const int*   ids  = (const int*)d_in[1];
  const float* gate = (const float*)d_in[2];
  const float* up   = (const float*)d_in[3];
  const float* down = (const float*)d_in[4];
  float* out = (float*)d_out;

  int T = in_sizes[0] / HIDDEN;              // 4096

  char* w = (char*)d_ws;
  int* hdr    = (int*)w;
  int* src_of = (int*)(w + 1024);
  size_t xg_off = (size_t)(1024 + ((4 * T + 255) & ~255));
  u16* Xg = (u16*)(w + xg_off);
  u16* Hb = Xg + (size_t)T * HIDDEN;

  int maxt = (T + 127) / 128 + (NEXP - 1);   // worst-case tile count

  route_kernel<<<1, 256, 0, stream>>>(ids, T, hdr, src_of);
  gather_kernel<<<T, 256, 0, stream>>>(x, src_of, Xg);
  gemm1_kernel<<<dim3(maxt, EINTER / 128), 256, 0, stream>>>(Xg, gate, up, Hb, hdr, T);
  gemm2_kernel<<<dim3(maxt, HIDDEN / 128), 256, 0, stream>>>(Hb, down, out, src_of, hdr, T);
}

// Round 2
// 365.042 us; speedup vs baseline: 1.2802x; 1.2802x over previous
//
#include <hip/hip_runtime.h>
#include <hip/hip_bf16.h>
#include <math.h>

#define HIDDEN 2048
#define EINTER 1024
#define NEXP 8
#define VOCAB 100000
#define TPE (VOCAB / NEXP)   // 12500

typedef unsigned short u16;
typedef __attribute__((ext_vector_type(8))) short short8;   // 8 bf16 (4 VGPRs)
typedef __attribute__((ext_vector_type(4))) float f32x4;

__device__ __forceinline__ u16 f2bf(float f) {
  union { float f; unsigned u; } v; v.f = f;
  unsigned r = v.u + 0x7fffu + ((v.u >> 16) & 1u);   // RNE, finite inputs only
  return (u16)(r >> 16);
}

// async global->LDS, 16B per lane; lds dest = wave-uniform base + lane*16
__device__ __forceinline__ void gl2lds16(const u16* g, u16* l) {
  __builtin_amdgcn_global_load_lds(
      (const __attribute__((address_space(1))) unsigned int*)g,
      (__attribute__((address_space(3))) unsigned int*)l, 16, 0, 0);
}

// ---------------- routing ----------------
// hdr ints: [0..7]=cnt[e], [8..15]=off[e], [16]=n_tiles, [32..95]=worklist
__global__ void route_kernel(const int* __restrict__ ids, int T,
                             int* __restrict__ hdr, int* __restrict__ src_of) {
  __shared__ int cnt[NEXP], cur[NEXP];
  int tid = threadIdx.x;
  if (tid < NEXP) cnt[tid] = 0;
  __syncthreads();
  for (int t = tid; t < T; t += blockDim.x) {
    int id = ids[t]; id = min(max(id, 0), VOCAB - 1);
    int e = min(id / TPE, NEXP - 1);
    atomicAdd(&cnt[e], 1);
  }
  __syncthreads();
  if (tid == 0) {
    int acc = 0, nt = 0;
    for (int e = 0; e < NEXP; e++) {
      cur[e] = acc;
      hdr[e] = cnt[e];
      hdr[8 + e] = acc;
      int tiles = (cnt[e] + 127) >> 7;
      for (int m = 0; m < tiles; m++) hdr[32 + nt++] = (m << 3) | e;
      acc += cnt[e];
    }
    hdr[16] = nt;
  }
  __syncthreads();
  for (int t = tid; t < T; t += blockDim.x) {
    int id = ids[t]; id = min(max(id, 0), VOCAB - 1);
    int e = min(id / TPE, NEXP - 1);
    int pos = atomicAdd(&cur[e], 1);
    src_of[pos] = t;
  }
}

// ---------------- weight transpose + bf16 convert ----------------
// W [K][N] fp32 -> Wt [N][K] bf16.  z=0 gate, z=1 up (K=2048,N=1024); z=2 down (K=1024,N=2048)
__global__ void prep_kernel(const float* __restrict__ gate, const float* __restrict__ up,
                            const float* __restrict__ down,
                            u16* __restrict__ gatet, u16* __restrict__ upt,
                            u16* __restrict__ downt) {
  int z = blockIdx.z, e = blockIdx.y;
  const float* W; u16* Wt; int K, N;
  if (z == 0)      { W = gate; Wt = gatet; K = 2048; N = 1024; }
  else if (z == 1) { W = up;   Wt = upt;   K = 2048; N = 1024; }
  else             { W = down; Wt = downt; K = 1024; N = 2048; }
  W  += (size_t)e * K * N;
  Wt += (size_t)e * K * N;
  int ntx = N >> 6;
  int tk = blockIdx.x / ntx, tn = blockIdx.x - tk * ntx;
  int k0 = tk << 6, n0 = tn << 6;

  __shared__ u16 tile[64][73];   // 73 stride: near-conflict-free both phases
  int t = threadIdx.x;
  int cr = t >> 4, cc = (t & 15) << 2;
  #pragma unroll
  for (int r = 0; r < 4; r++) {
    int kk = (r << 4) + cr;
    float4 v = *(const float4*)(W + (size_t)(k0 + kk) * N + n0 + cc);
    tile[kk][cc] = f2bf(v.x); tile[kk][cc + 1] = f2bf(v.y);
    tile[kk][cc + 2] = f2bf(v.z); tile[kk][cc + 3] = f2bf(v.w);
  }
  __syncthreads();
  int wr = t >> 3, wc = (t & 7) << 3;
  #pragma unroll
  for (int r = 0; r < 2; r++) {
    int nn = (r << 5) + wr;
    union { u16 s[8]; uint4 v; } o;
    #pragma unroll
    for (int j = 0; j < 8; j++) o.s[j] = tile[wc + j][nn];
    *(uint4*)(Wt + (size_t)(n0 + nn) * K + k0 + wc) = o.v;
  }
}

// ---------------- gather tokens -> bf16 rows ----------------
__global__ void gather_kernel(const float* __restrict__ x,
                              const int* __restrict__ src_of,
                              u16* __restrict__ Xg) {
  int p = blockIdx.x;
  int t = src_of[p];
  int c = threadIdx.x;
  const float4* src = (const float4*)(x + (size_t)t * HIDDEN) + c * 2;
  float4 a = src[0], b = src[1];
  union { u16 s[8]; uint4 v; } o;
  o.s[0] = f2bf(a.x); o.s[1] = f2bf(a.y); o.s[2] = f2bf(a.z); o.s[3] = f2bf(a.w);
  o.s[4] = f2bf(b.x); o.s[5] = f2bf(b.y); o.s[6] = f2bf(b.z); o.s[7] = f2bf(b.w);
  *((uint4*)(Xg + (size_t)p * HIDDEN) + c) = o.v;
}

// ---------------- gemm1: G = Xg@gate^T' , U = Xg@up^T'  (z selects) ----------------
__launch_bounds__(256, 3)
__global__ void gemm1_kernel(const u16* __restrict__ Xg, const u16* __restrict__ gatet,
                             const u16* __restrict__ upt, float* __restrict__ Gbuf,
                             float* __restrict__ Ubuf, const int* __restrict__ hdr, int T) {
  int ntile = hdr[16];
  if ((int)blockIdx.x >= ntile) return;
  int packed = hdr[32 + blockIdx.x];
  int e = packed & 7, mt = packed >> 3;
  int Me = hdr[e], base = hdr[8 + e];
  int row0 = base + (mt << 7);
  int valid = min(128, base + Me - row0);
  int n0 = blockIdx.y << 7;
  const u16* wbase = (blockIdx.z ? upt : gatet) + (size_t)e * (2048 * 1024);
  float* Obuf = blockIdx.z ? Ubuf : Gbuf;

  __shared__ u16 As[128][64];   // [m][k] 16 KB
  __shared__ u16 Bs[128][64];   // [n][k] 16 KB

  int tid = threadIdx.x, lane = tid & 63, wv = tid >> 6;
  int wm = wv >> 1, wn = wv & 1;
  int quad = lane >> 4, ln = lane & 15;
  int srow = lane >> 3, schunk = lane & 7;

  f32x4 acc[4][4] = {};

  for (int k0 = 0; k0 < 2048; k0 += 64) {
    __syncthreads();
    #pragma unroll
    for (int r = 0; r < 4; r++) {
      int c = (wv << 2) + r;                 // 0..15
      int arow = (c << 3) + srow;
      int gr = min(row0 + arow, T - 1);      // clamp: masked rows duplicate a real row
      gl2lds16(Xg + (size_t)gr * 2048 + k0 + (schunk << 3), &As[0][0] + (c << 9));
    }
    #pragma unroll
    for (int r = 0; r < 4; r++) {
      int c = (wv << 2) + r;
      int brow = (c << 3) + srow;
      gl2lds16(wbase + (size_t)(n0 + brow) * 2048 + k0 + (schunk << 3), &Bs[0][0] + (c << 9));
    }
    __syncthreads();
    #pragma unroll
    for (int s = 0; s < 2; s++) {
      short8 a[4], b[4];
      #pragma unroll
      for (int i = 0; i < 4; i++) {
        int m = (wm << 6) + (i << 4) + ln;
        a[i] = *(const short8*)&As[m][(s << 5) + (quad << 3)];
        int n = (wn << 6) + (i << 4) + ln;
        b[i] = *(const short8*)&Bs[n][(s << 5) + (quad << 3)];
      }
      #pragma unroll
      for (int i = 0; i < 4; i++)
        #pragma unroll
        for (int j = 0; j < 4; j++)
          acc[i][j] = __builtin_amdgcn_mfma_f32_16x16x32_bf16(a[i], b[j], acc[i][j], 0, 0, 0);
    }
  }
  #pragma unroll
  for (int i = 0; i < 4; i++) {
    #pragma unroll
    for (int r = 0; r < 4; r++) {
      int rl = (wm << 6) + (i << 4) + (quad << 2) + r;
      if (rl < valid) {
        float* orow = Obuf + (size_t)(row0 + rl) * EINTER + n0 + (wn << 6) + ln;
        #pragma unroll
        for (int j = 0; j < 4; j++) orow[j << 4] = acc[i][j][r];
      }
    }
  }
}

// ---------------- silu-mul: H = silu(G)*U (bf16) ----------------
__global__ void silu_kernel(const float* __restrict__ G, const float* __restrict__ U,
                            u16* __restrict__ H) {
  int idx = blockIdx.x * 256 + threadIdx.x;
  float4 g = ((const float4*)G)[idx];
  float4 u = ((const float4*)U)[idx];
  union { u16 s[4]; uint2 v; } o;
  o.s[0] = f2bf(g.x / (1.f + __expf(-g.x)) * u.x);
  o.s[1] = f2bf(g.y / (1.f + __expf(-g.y)) * u.y);
  o.s[2] = f2bf(g.z / (1.f + __expf(-g.z)) * u.z);
  o.s[3] = f2bf(g.w / (1.f + __expf(-g.w)) * u.w);
  ((uint2*)H)[idx] = o.v;
}

// ---------------- gemm2: out[src_of[p]] = H[p] @ down ----------------
__launch_bounds__(256, 3)
__global__ void gemm2_kernel(const u16* __restrict__ Hb, const u16* __restrict__ downt,
                             float* __restrict__ out, const int* __restrict__ src_of,
                             const int* __restrict__ hdr, int T) {
  int ntile = hdr[16];
  if ((int)blockIdx.x >= ntile) return;
  int packed = hdr[32 + blockIdx.x];
  int e = packed & 7, mt = packed >> 3;
  int Me = hdr[e], base = hdr[8 + e];
  int row0 = base + (mt << 7);
  int valid = min(128, base + Me - row0);
  int n0 = blockIdx.y << 7;
  const u16* wbase = downt + (size_t)e * (2048 * 1024);

  __shared__ u16 As[128][64];
  __shared__ u16 Bs[128][64];

  int tid = threadIdx.x, lane = tid & 63, wv = tid >> 6;
  int wm = wv >> 1, wn = wv & 1;
  int quad = lane >> 4, ln = lane & 15;
  int srow = lane >> 3, schunk = lane & 7;

  f32x4 acc[4][4] = {};

  for (int k0 = 0; k0 < 1024; k0 += 64) {
    __syncthreads();
    #pragma unroll
    for (int r = 0; r < 4; r++) {
      int c = (wv << 2) + r;
      int arow = (c << 3) + srow;
      int gr = min(row0 + arow, T - 1);
      gl2lds16(Hb + (size_t)gr * 1024 + k0 + (schunk << 3), &As[0][0] + (c << 9));
    }
    #pragma unroll
    for (int r = 0; r < 4; r++) {
      int c = (wv << 2) + r;
      int brow = (c << 3) + srow;
      gl2lds16(wbase + (size_t)(n0 + brow) * 1024 + k0 + (schunk << 3), &Bs[0][0] + (c << 9));
    }
    __syncthreads();
    #pragma unroll
    for (int s = 0; s < 2; s++) {
      short8 a[4], b[4];
      #pragma unroll
      for (int i = 0; i < 4; i++) {
        int m = (wm << 6) + (i << 4) + ln;
        a[i] = *(const short8*)&As[m][(s << 5) + (quad << 3)];
        int n = (wn << 6) + (i << 4) + ln;
        b[i] = *(const short8*)&Bs[n][(s << 5) + (quad << 3)];
      }
      #pragma unroll
      for (int i = 0; i < 4; i++)
        #pragma unroll
        for (int j = 0; j < 4; j++)
          acc[i][j] = __builtin_amdgcn_mfma_f32_16x16x32_bf16(a[i], b[j], acc[i][j], 0, 0, 0);
    }
  }
  #pragma unroll
  for (int i = 0; i < 4; i++) {
    #pragma unroll
    for (int r = 0; r < 4; r++) {
      int rl = (wm << 6) + (i << 4) + (quad << 2) + r;
      if (rl < valid) {
        int t = src_of[row0 + rl];
        float* orow = out + (size_t)t * HIDDEN + n0 + (wn << 6) + ln;
        #pragma unroll
        for (int j = 0; j < 4; j++) orow[j << 4] = acc[i][j][r];
      }
    }
  }
}

extern "C" void kernel_launch(void* const* d_in, const int* in_sizes, int n_in,
                              void* d_out, int out_size, void* d_ws, size_t ws_size,
                              hipStream_t stream) {
  const float* x    = (const float*)d_in[0];
  const int*   ids  = (const int*)d_in[1];
  const float* gate = (const float*)d_in[2];
  const float* up   = (const float*)d_in[3];
  const float* down = (const float*)d_in[4];
  float* out = (float*)d_out;

  int T = in_sizes[0] / HIDDEN;              // 4096

  // ws layout (all 256-aligned):
  char* w = (char*)d_ws;
  int* hdr    = (int*)w;                                   // 1 KB
  int* src_of = (int*)(w + 1024);                          // 16 KB
  size_t off = 1024 + (size_t)T * 4;                       // 17408, 16B aligned
  u16* Xg   = (u16*)(w + off);  off += (size_t)T * HIDDEN * 2;     // 16.8 MB
  u16* Hb   = (u16*)(w + off);  off += (size_t)T * EINTER * 2;     // 8.4 MB
  float* Gb = (float*)(w + off); off += (size_t)T * EINTER * 4;    // 16.8 MB
  float* Ub = (float*)(w + off); off += (size_t)T * EINTER * 4;    // 16.8 MB
  u16* gatet = (u16*)(w + off); off += (size_t)NEXP * HIDDEN * EINTER * 2;  // 33.6 MB
  u16* upt   = (u16*)(w + off); off += (size_t)NEXP * HIDDEN * EINTER * 2;  // 33.6 MB
  u16* downt = (u16*)(w + off); off += (size_t)NEXP * HIDDEN * EINTER * 2;  // 33.6 MB

  int maxt = (T + 127) / 128 + (NEXP - 1) + 1;   // 40 worst-case tiles

  prep_kernel<<<dim3(512, NEXP, 3), 256, 0, stream>>>(gate, up, down, gatet, upt, downt);
  route_kernel<<<1, 256, 0, stream>>>(ids, T, hdr, src_of);
  gather_kernel<<<T, 256, 0, stream>>>(x, src_of, Xg);
  gemm1_kernel<<<dim3(maxt, EINTER / 128, 2), 256, 0, stream>>>(Xg, gatet, upt, Gb, Ub, hdr, T);
  silu_kernel<<<(T * EINTER / 4) / 256, 256, 0, stream>>>(Gb, Ub, Hb);
  gemm2_kernel<<<dim3(maxt, HIDDEN / 128), 256, 0, stream>>>(Hb, downt, out, src_of, hdr, T);
}